// Round 1
// baseline (1088.368 us; speedup 1.0000x reference)
//
#include <hip/hip_runtime.h>
#include <math.h>

// PhiDecoderLayer on MI355X. B=2, S=2048, E=2048, MLP=8192, fp32 in/out.
// Strategy: all GEMMs in bf16 MFMA 16x16x32 w/ fp32 accum; fp32->bf16
// conversion fused into LDS staging. Workspace use: 256 MiB.

#define SEQ 2048
#define EMB 2048
#define MLPD 8192

typedef __attribute__((ext_vector_type(8))) short short8;
typedef __attribute__((ext_vector_type(4))) float floatx4;

__device__ __forceinline__ short f2bf(float f) {
  union { float f; unsigned u; } v; v.f = f;
  unsigned r = v.u + 0x7FFFu + ((v.u >> 16) & 1u);
  return (short)(r >> 16);
}

enum { EPI_QKV = 0, EPI_SCORES = 1, EPI_PV = 2, EPI_RES = 3, EPI_GELU = 4 };

// C[M][N] = A[M][K] * B[N][K]^T  (both operands contracted over K)
// A, B are fp32 or bf16(ushort) per template; LDS staging converts to bf16.
template<int EPI, bool AF32, bool BF32>
__global__ __launch_bounds__(256)
void gemm_bt(const void* __restrict__ Ap, const void* __restrict__ Bp,
             const float* __restrict__ bias, const float* __restrict__ res,
             void* __restrict__ Cp, int M, int N, int K,
             long sA, long sB, long sC, float scale)
{
  constexpr int BM = 128, BN = 128, BK = 32, LDK = 40; // pad 32->40 (80B rows)
  __shared__ short As[BM][LDK];
  __shared__ short Bs[BN][LDK];

  const int t = threadIdx.x;
  const int lane = t & 63, wid = t >> 6;
  const int wm = wid >> 1, wn = wid & 1;     // 2x2 waves, 64x64 each
  const long bm = (long)blockIdx.y * BM;
  const long bn = (long)blockIdx.x * BN;
  const int z = blockIdx.z;

  const float* Af = ((const float*)Ap) + (long)z * sA;
  const unsigned short* Ab = ((const unsigned short*)Ap) + (long)z * sA;
  const float* Bf = ((const float*)Bp) + (long)z * sB;
  const unsigned short* Bb = ((const unsigned short*)Bp) + (long)z * sB;

  floatx4 acc[4][4];
#pragma unroll
  for (int m = 0; m < 4; ++m)
#pragma unroll
    for (int n = 0; n < 4; ++n) acc[m][n] = (floatx4)0.0f;

  const int l15 = lane & 15, kq = (lane >> 4) * 8;

  for (int kb = 0; kb < K; kb += BK) {
    // ---- stage A and B tiles (128x32 each), 8 elems per thread per iter ----
#pragma unroll
    for (int i = 0; i < 2; ++i) {
      const int idx = t * 8 + i * 2048;     // 0..4095, step 8
      const int row = idx >> 5;             // 0..127
      const int k0 = idx & 31;              // 0,8,16,24
      short8 va, vb;
      if constexpr (AF32) {
        const float* src = Af + (bm + row) * (long)K + kb + k0;
        float4 f0 = *reinterpret_cast<const float4*>(src);
        float4 f1 = *reinterpret_cast<const float4*>(src + 4);
        va[0] = f2bf(f0.x); va[1] = f2bf(f0.y); va[2] = f2bf(f0.z); va[3] = f2bf(f0.w);
        va[4] = f2bf(f1.x); va[5] = f2bf(f1.y); va[6] = f2bf(f1.z); va[7] = f2bf(f1.w);
      } else {
        const unsigned short* src = Ab + (bm + row) * (long)K + kb + k0;
        va = *reinterpret_cast<const short8*>(src);
      }
      if constexpr (BF32) {
        const float* src = Bf + (bn + row) * (long)K + kb + k0;
        float4 f0 = *reinterpret_cast<const float4*>(src);
        float4 f1 = *reinterpret_cast<const float4*>(src + 4);
        vb[0] = f2bf(f0.x); vb[1] = f2bf(f0.y); vb[2] = f2bf(f0.z); vb[3] = f2bf(f0.w);
        vb[4] = f2bf(f1.x); vb[5] = f2bf(f1.y); vb[6] = f2bf(f1.z); vb[7] = f2bf(f1.w);
      } else {
        const unsigned short* src = Bb + (bn + row) * (long)K + kb + k0;
        vb = *reinterpret_cast<const short8*>(src);
      }
      *reinterpret_cast<short8*>(&As[row][k0]) = va;
      *reinterpret_cast<short8*>(&Bs[row][k0]) = vb;
    }
    __syncthreads();

    // ---- compute: each wave 4x4 fragments of 16x16, one K=32 step ----
    short8 a[4], b[4];
#pragma unroll
    for (int m = 0; m < 4; ++m)
      a[m] = *reinterpret_cast<const short8*>(&As[wm * 64 + m * 16 + l15][kq]);
#pragma unroll
    for (int n = 0; n < 4; ++n)
      b[n] = *reinterpret_cast<const short8*>(&Bs[wn * 64 + n * 16 + l15][kq]);
#pragma unroll
    for (int m = 0; m < 4; ++m)
#pragma unroll
      for (int n = 0; n < 4; ++n)
        acc[m][n] = __builtin_amdgcn_mfma_f32_16x16x32_bf16(a[m], b[n], acc[m][n], 0, 0, 0);
    __syncthreads();
  }

  // ---- epilogue: C/D layout col=lane&15, row=(lane>>4)*4+i ----
  const int lq = lane >> 4;
#pragma unroll
  for (int m = 0; m < 4; ++m) {
#pragma unroll
    for (int n = 0; n < 4; ++n) {
#pragma unroll
      for (int i = 0; i < 4; ++i) {
        const long r = bm + wm * 64 + m * 16 + lq * 4 + i;
        const long c = bn + wn * 64 + n * 16 + l15;
        float val = acc[m][n][i];
        if constexpr (EPI == EPI_QKV) {
          val += bias[c];
          ((unsigned short*)Cp)[(long)z * sC + r * N + c] = (unsigned short)f2bf(val);
        } else if constexpr (EPI == EPI_SCORES) {
          ((float*)Cp)[(long)z * sC + r * N + c] = val * scale;
        } else if constexpr (EPI == EPI_PV) {
          ((unsigned short*)Cp)[(long)z * sC + r * N + c] = (unsigned short)f2bf(val);
        } else if constexpr (EPI == EPI_RES) {
          val += bias[c] + res[r * N + c];
          ((float*)Cp)[r * N + c] = val;
        } else { // EPI_GELU (exact)
          val += bias[c];
          float g = 0.5f * val * (1.0f + erff(val * 0.70710678118f));
          ((unsigned short*)Cp)[r * N + c] = (unsigned short)f2bf(g);
        }
      }
    }
  }
}

// v [4096][2048] bf16 -> vT [2][2048][2048] bf16 (vT[b][e][s] = v[b*S+s][e])
__global__ __launch_bounds__(256)
void transpose_v(const unsigned short* __restrict__ v, unsigned short* __restrict__ vT)
{
  __shared__ unsigned short tile[32][33];
  const int b = blockIdx.z;
  const int s0 = blockIdx.x * 32, e0 = blockIdx.y * 32;
  const int tx = threadIdx.x & 31, ty = threadIdx.x >> 5;
#pragma unroll
  for (int i = 0; i < 4; ++i) {
    const int s = s0 + ty + i * 8;
    tile[ty + i * 8][tx] = v[((long)b * SEQ + s) * EMB + e0 + tx];
  }
  __syncthreads();
#pragma unroll
  for (int i = 0; i < 4; ++i) {
    const int e = e0 + ty + i * 8;
    vT[(long)b * SEQ * EMB + (long)e * SEQ + s0 + tx] = tile[tx][ty + i * 8];
  }
}

// row softmax: scores fp32 [4096][2048] -> probs bf16
__global__ __launch_bounds__(256)
void softmax_rows(const float* __restrict__ S, unsigned short* __restrict__ P)
{
  const long row = blockIdx.x;
  const float* src = S + row * 2048;
  const int t = threadIdx.x, lane = t & 63, wid = t >> 6;
  float4 a = *reinterpret_cast<const float4*>(src + t * 8);
  float4 b = *reinterpret_cast<const float4*>(src + t * 8 + 4);
  float v[8] = {a.x, a.y, a.z, a.w, b.x, b.y, b.z, b.w};
  float m = v[0];
#pragma unroll
  for (int i = 1; i < 8; ++i) m = fmaxf(m, v[i]);
#pragma unroll
  for (int o = 32; o; o >>= 1) m = fmaxf(m, __shfl_xor(m, o));
  __shared__ float rm[4], rs[4];
  if (!lane) rm[wid] = m;
  __syncthreads();
  m = fmaxf(fmaxf(rm[0], rm[1]), fmaxf(rm[2], rm[3]));
  float e[8], s = 0.f;
#pragma unroll
  for (int i = 0; i < 8; ++i) { e[i] = __expf(v[i] - m); s += e[i]; }
#pragma unroll
  for (int o = 32; o; o >>= 1) s += __shfl_xor(s, o);
  if (!lane) rs[wid] = s;
  __syncthreads();
  s = rs[0] + rs[1] + rs[2] + rs[3];
  const float inv = 1.0f / s;
  short8 w;
#pragma unroll
  for (int i = 0; i < 8; ++i) w[i] = f2bf(e[i] * inv);
  *reinterpret_cast<short8*>(P + row * 2048 + t * 8) = w;
}

// layernorm rows: t fp32 [4096][2048] -> h fp32
__global__ __launch_bounds__(256)
void layernorm_rows(const float* __restrict__ X, const float* __restrict__ g,
                    const float* __restrict__ bb, float* __restrict__ H)
{
  const long row = blockIdx.x;
  const float* src = X + row * 2048;
  const int t = threadIdx.x, lane = t & 63, wid = t >> 6;
  float4 a = *reinterpret_cast<const float4*>(src + t * 8);
  float4 b = *reinterpret_cast<const float4*>(src + t * 8 + 4);
  float v[8] = {a.x, a.y, a.z, a.w, b.x, b.y, b.z, b.w};
  float s = 0.f, ss = 0.f;
#pragma unroll
  for (int i = 0; i < 8; ++i) { s += v[i]; ss += v[i] * v[i]; }
#pragma unroll
  for (int o = 32; o; o >>= 1) { s += __shfl_xor(s, o); ss += __shfl_xor(ss, o); }
  __shared__ float r1[4], r2[4];
  if (!lane) { r1[wid] = s; r2[wid] = ss; }
  __syncthreads();
  s = r1[0] + r1[1] + r1[2] + r1[3];
  ss = r2[0] + r2[1] + r2[2] + r2[3];
  const float mu = s * (1.0f / 2048.0f);
  const float var = ss * (1.0f / 2048.0f) - mu * mu;
  const float inv = rsqrtf(var + 1e-5f);
  float o0[8];
#pragma unroll
  for (int i = 0; i < 8; ++i) {
    const int c = t * 8 + i;
    o0[i] = (v[i] - mu) * inv * g[c] + bb[c];
  }
  float4 w0 = {o0[0], o0[1], o0[2], o0[3]}, w1 = {o0[4], o0[5], o0[6], o0[7]};
  *reinterpret_cast<float4*>(H + row * 2048 + t * 8) = w0;
  *reinterpret_cast<float4*>(H + row * 2048 + t * 8 + 4) = w1;
}

extern "C" void kernel_launch(void* const* d_in, const int* in_sizes, int n_in,
                              void* d_out, int out_size, void* d_ws, size_t ws_size,
                              hipStream_t stream) {
  const float* x    = (const float*)d_in[0];
  const float* wq   = (const float*)d_in[1];
  const float* bq   = (const float*)d_in[2];
  const float* wk   = (const float*)d_in[3];
  const float* bk   = (const float*)d_in[4];
  const float* wv   = (const float*)d_in[5];
  const float* bv   = (const float*)d_in[6];
  const float* wd   = (const float*)d_in[7];
  const float* bd   = (const float*)d_in[8];
  const float* ln_g = (const float*)d_in[9];
  const float* ln_b = (const float*)d_in[10];
  const float* w1   = (const float*)d_in[11];
  const float* b1   = (const float*)d_in[12];
  const float* w2   = (const float*)d_in[13];
  const float* b2   = (const float*)d_in[14];
  float* out = (float*)d_out;

  // workspace layout (total = 256 MiB)
  char* ws = (char*)d_ws;
  unsigned short* qb    = (unsigned short*)ws;  ws += 16777216; // 4096x2048 bf16
  unsigned short* kb    = (unsigned short*)ws;  ws += 16777216;
  unsigned short* vb    = (unsigned short*)ws;  ws += 16777216;
  unsigned short* vT    = (unsigned short*)ws;  ws += 16777216;
  unsigned short* probs = (unsigned short*)ws;  ws += 16777216;
  unsigned short* ctx   = (unsigned short*)ws;  ws += 16777216;
  float* scores = (float*)ws;  ws += 33554432;  // 2x2048x2048 f32
  float* tres   = (float*)ws;  ws += 33554432;  // x + attn_out
  float* h      = (float*)ws;  ws += 33554432;  // layernorm output
  unsigned short* mlp = (unsigned short*)ws;    // 4096x8192 bf16 (67 MiB)

  const long SQ = (long)SEQ * SEQ;
  const dim3 blk(256);

  // QKV projections: [4096,2048] x [2048,2048]^T
  gemm_bt<EPI_QKV, true, true><<<dim3(16, 32, 1), blk, 0, stream>>>(
      x, wq, bq, nullptr, qb, 4096, EMB, EMB, 0, 0, 0, 1.f);
  gemm_bt<EPI_QKV, true, true><<<dim3(16, 32, 1), blk, 0, stream>>>(
      x, wk, bk, nullptr, kb, 4096, EMB, EMB, 0, 0, 0, 1.f);
  gemm_bt<EPI_QKV, true, true><<<dim3(16, 32, 1), blk, 0, stream>>>(
      x, wv, bv, nullptr, vb, 4096, EMB, EMB, 0, 0, 0, 1.f);

  transpose_v<<<dim3(64, 64, 2), blk, 0, stream>>>(vb, vT);

  // scores = q k^T / sqrt(E), per batch
  gemm_bt<EPI_SCORES, false, false><<<dim3(16, 16, 2), blk, 0, stream>>>(
      qb, kb, nullptr, nullptr, scores, SEQ, SEQ, EMB, SQ, SQ, SQ, 0.022097086912079608f);

  softmax_rows<<<dim3(4096), blk, 0, stream>>>(scores, probs);

  // ctx = probs @ v  (vT is [E][S] per batch -> B^T layout)
  gemm_bt<EPI_PV, false, false><<<dim3(16, 16, 2), blk, 0, stream>>>(
      probs, vT, nullptr, nullptr, ctx, SEQ, EMB, SEQ, SQ, SQ, SQ, 1.f);

  // t = x + ctx @ wd^T + bd
  gemm_bt<EPI_RES, false, true><<<dim3(16, 32, 1), blk, 0, stream>>>(
      ctx, wd, bd, x, tres, 4096, EMB, EMB, 0, 0, 0, 1.f);

  layernorm_rows<<<dim3(4096), blk, 0, stream>>>(tres, ln_g, ln_b, h);

  // mlp = gelu(h @ w1^T + b1)
  gemm_bt<EPI_GELU, true, true><<<dim3(64, 32, 1), blk, 0, stream>>>(
      h, w1, b1, nullptr, mlp, 4096, MLPD, EMB, 0, 0, 0, 1.f);

  // out = h + mlp @ w2^T + b2
  gemm_bt<EPI_RES, false, true><<<dim3(16, 32, 1), blk, 0, stream>>>(
      mlp, w2, b2, h, out, 4096, EMB, MLPD, 0, 0, 0, 1.f);
}

// Round 2
// 873.708 us; speedup vs baseline: 1.2457x; 1.2457x over previous
//
#include <hip/hip_runtime.h>
#include <math.h>

// PhiDecoderLayer on MI355X. B=2, S=2048, E=2048, MLP=8192, fp32 in/out.
// Round 2: m97-structure GEMM (global_load_lds width-16, linear LDS,
// 128x128 tile, BK=32, 2-barrier K-loop) over pre-converted bf16 operands.

#define SEQ 2048
#define EMB 2048
#define MLPD 8192

typedef __attribute__((ext_vector_type(8))) short short8;
typedef __attribute__((ext_vector_type(4))) float floatx4;
typedef unsigned short ushort;

__device__ __forceinline__ short f2bf(float f) {
  union { float f; unsigned u; } v; v.f = f;
  unsigned r = v.u + 0x7FFFu + ((v.u >> 16) & 1u);
  return (short)(r >> 16);
}

// async global->LDS, 16B per lane. LDS dest = wave-uniform base + lane*16.
__device__ __forceinline__ void gload16(const ushort* g, ushort* l) {
  __builtin_amdgcn_global_load_lds(
      (__attribute__((address_space(1))) void*)g,
      (__attribute__((address_space(3))) void*)(unsigned)(unsigned long)l,
      16, 0, 0);
}

enum { EPI_QKV = 0, EPI_SCORES = 1, EPI_PV = 2, EPI_RES = 3, EPI_GELU = 4 };

// C[M][N] = A[M][K] * B[N][K]^T ; A,B bf16 (ushort), strides in elements.
// M = gridDim.y*128. z batches via sA/sB/sC.
template<int EPI>
__global__ __launch_bounds__(256)
void gemm_bt(const ushort* __restrict__ A, const ushort* __restrict__ B,
             const float* __restrict__ bias, const float* __restrict__ res,
             void* __restrict__ Cp, int N, int K,
             int lda, int ldb, int ldc,
             long sA, long sB, long sC, float scale)
{
  __shared__ ushort As[128 * 32];   // linear row-major [128][32], 8 KiB
  __shared__ ushort Bs[128 * 32];

  const int t = threadIdx.x;
  const int lane = t & 63, wid = t >> 6;
  const int wm = wid >> 1, wn = wid & 1;         // 2x2 waves of 64x64
  const long bm = (long)blockIdx.y * 128;
  const long bn = (long)blockIdx.x * 128;
  A += (long)blockIdx.z * sA;
  B += (long)blockIdx.z * sB;

  // staging geometry: wave wid covers rows [wid*32, wid*32+32), two 1KiB
  // issues of 16 rows each; lane covers 16B at row=lane/4, col=(lane&3)*8.
  const int srow = (wid << 5) + (lane >> 2);
  const int scol = (lane & 3) << 3;
  const ushort* a0 = A + (bm + srow) * (long)lda + scol;
  const ushort* a1 = a0 + 16L * lda;
  const ushort* b0 = B + (bn + srow) * (long)ldb + scol;
  const ushort* b1 = b0 + 16L * ldb;
  ushort* lA0 = As + (wid << 10);  // wave-uniform LDS bases (bytes wid*2048)
  ushort* lA1 = lA0 + 512;
  ushort* lB0 = Bs + (wid << 10);
  ushort* lB1 = lB0 + 512;

  floatx4 acc[4][4];
#pragma unroll
  for (int m = 0; m < 4; ++m)
#pragma unroll
    for (int n = 0; n < 4; ++n) acc[m][n] = (floatx4)0.0f;

  const int l15 = lane & 15, kq = (lane >> 4) << 3;
  const int abase = ((wm << 6) + l15) * 32 + kq;  // As elem idx, m=0 fragment
  const int bbase = ((wn << 6) + l15) * 32 + kq;

  for (int kb = 0; kb < K; kb += 32) {
    gload16(a0 + kb, lA0);
    gload16(a1 + kb, lA1);
    gload16(b0 + kb, lB0);
    gload16(b1 + kb, lB1);
    __syncthreads();                 // compiler drains vmcnt before barrier

    short8 a[4], b[4];
#pragma unroll
    for (int m = 0; m < 4; ++m)
      a[m] = *reinterpret_cast<const short8*>(&As[abase + m * (16 * 32)]);
#pragma unroll
    for (int n = 0; n < 4; ++n)
      b[n] = *reinterpret_cast<const short8*>(&Bs[bbase + n * (16 * 32)]);
#pragma unroll
    for (int m = 0; m < 4; ++m)
#pragma unroll
      for (int n = 0; n < 4; ++n)
        acc[m][n] = __builtin_amdgcn_mfma_f32_16x16x32_bf16(a[m], b[n], acc[m][n], 0, 0, 0);
    __syncthreads();                 // protect LDS from next stage
  }

  // epilogue: C/D map col=lane&15, row=(lane>>4)*4+i
  const int lq = lane >> 4;
#pragma unroll
  for (int m = 0; m < 4; ++m) {
#pragma unroll
    for (int n = 0; n < 4; ++n) {
#pragma unroll
      for (int i = 0; i < 4; ++i) {
        const long r = bm + wm * 64 + m * 16 + lq * 4 + i;
        const long c = bn + wn * 64 + n * 16 + l15;
        float val = acc[m][n][i];
        if constexpr (EPI == EPI_QKV) {
          val += bias[c];
          ((ushort*)Cp)[r * (long)ldc + c] = (ushort)f2bf(val);
        } else if constexpr (EPI == EPI_SCORES) {
          ((float*)Cp)[(long)blockIdx.z * sC + r * (long)ldc + c] = val * scale;
        } else if constexpr (EPI == EPI_PV) {
          ((ushort*)Cp)[(long)blockIdx.z * sC + r * (long)ldc + c] = (ushort)f2bf(val);
        } else if constexpr (EPI == EPI_RES) {
          val += bias[c] + res[r * (long)ldc + c];
          ((float*)Cp)[r * (long)ldc + c] = val;
        } else {  // EPI_GELU exact
          val += bias[c];
          float g = 0.5f * val * (1.0f + erff(val * 0.70710678118f));
          ((ushort*)Cp)[r * (long)ldc + c] = (ushort)f2bf(g);
        }
      }
    }
  }
}

// fp32 -> bf16, 8 elems/thread, exact grid (n divisible by 2048)
__global__ __launch_bounds__(256)
void cvt8(const float* __restrict__ s, ushort* __restrict__ d) {
  const long i = ((long)blockIdx.x * 256 + threadIdx.x) * 8;
  float4 a = *reinterpret_cast<const float4*>(s + i);
  float4 b = *reinterpret_cast<const float4*>(s + i + 4);
  short8 v;
  v[0] = f2bf(a.x); v[1] = f2bf(a.y); v[2] = f2bf(a.z); v[3] = f2bf(a.w);
  v[4] = f2bf(b.x); v[5] = f2bf(b.y); v[6] = f2bf(b.z); v[7] = f2bf(b.w);
  *reinterpret_cast<short8*>(d + i) = v;
}

__global__ __launch_bounds__(256)
void concat3(const float* __restrict__ b0, const float* __restrict__ b1,
             const float* __restrict__ b2, float* __restrict__ dst) {
  const int i = blockIdx.x * 256 + threadIdx.x;  // 6144 total
  dst[i] = (i < 2048) ? b0[i] : (i < 4096) ? b1[i - 2048] : b2[i - 4096];
}

// v lives strided inside qkv: v[b*S+s][e] = qkv[(b*S+s)*6144 + 4096 + e]
// -> vT[b][e][s]
__global__ __launch_bounds__(256)
void transpose_v(const ushort* __restrict__ qkv, ushort* __restrict__ vT) {
  __shared__ ushort tile[32][33];
  const int b = blockIdx.z;
  const int s0 = blockIdx.x * 32, e0 = blockIdx.y * 32;
  const int tx = threadIdx.x & 31, ty = threadIdx.x >> 5;
#pragma unroll
  for (int i = 0; i < 4; ++i) {
    const long s = (long)b * SEQ + s0 + ty + i * 8;
    tile[ty + i * 8][tx] = qkv[s * 6144 + 4096 + e0 + tx];
  }
  __syncthreads();
#pragma unroll
  for (int i = 0; i < 4; ++i) {
    const long e = (long)b * SEQ + e0 + ty + i * 8;
    vT[e * SEQ + s0 + tx] = tile[tx][ty + i * 8];
  }
}

__global__ __launch_bounds__(256)
void softmax_rows(const float* __restrict__ S, ushort* __restrict__ P) {
  const long row = blockIdx.x;
  const float* src = S + row * 2048;
  const int t = threadIdx.x, lane = t & 63, wid = t >> 6;
  float4 a = *reinterpret_cast<const float4*>(src + t * 8);
  float4 b = *reinterpret_cast<const float4*>(src + t * 8 + 4);
  float v[8] = {a.x, a.y, a.z, a.w, b.x, b.y, b.z, b.w};
  float m = v[0];
#pragma unroll
  for (int i = 1; i < 8; ++i) m = fmaxf(m, v[i]);
#pragma unroll
  for (int o = 32; o; o >>= 1) m = fmaxf(m, __shfl_xor(m, o));
  __shared__ float rm[4], rs[4];
  if (!lane) rm[wid] = m;
  __syncthreads();
  m = fmaxf(fmaxf(rm[0], rm[1]), fmaxf(rm[2], rm[3]));
  float e[8], s = 0.f;
#pragma unroll
  for (int i = 0; i < 8; ++i) { e[i] = __expf(v[i] - m); s += e[i]; }
#pragma unroll
  for (int o = 32; o; o >>= 1) s += __shfl_xor(s, o);
  if (!lane) rs[wid] = s;
  __syncthreads();
  s = rs[0] + rs[1] + rs[2] + rs[3];
  const float inv = 1.0f / s;
  short8 w;
#pragma unroll
  for (int i = 0; i < 8; ++i) w[i] = f2bf(e[i] * inv);
  *reinterpret_cast<short8*>(P + row * 2048 + t * 8) = w;
}

// layernorm rows + bf16 copy of result
__global__ __launch_bounds__(256)
void layernorm_rows(const float* __restrict__ X, const float* __restrict__ g,
                    const float* __restrict__ bb, float* __restrict__ H,
                    ushort* __restrict__ Hb) {
  const long row = blockIdx.x;
  const float* src = X + row * 2048;
  const int t = threadIdx.x, lane = t & 63, wid = t >> 6;
  float4 a = *reinterpret_cast<const float4*>(src + t * 8);
  float4 b = *reinterpret_cast<const float4*>(src + t * 8 + 4);
  float v[8] = {a.x, a.y, a.z, a.w, b.x, b.y, b.z, b.w};
  float s = 0.f, ss = 0.f;
#pragma unroll
  for (int i = 0; i < 8; ++i) { s += v[i]; ss += v[i] * v[i]; }
#pragma unroll
  for (int o = 32; o; o >>= 1) { s += __shfl_xor(s, o); ss += __shfl_xor(ss, o); }
  __shared__ float r1[4], r2[4];
  if (!lane) { r1[wid] = s; r2[wid] = ss; }
  __syncthreads();
  s = r1[0] + r1[1] + r1[2] + r1[3];
  ss = r2[0] + r2[1] + r2[2] + r2[3];
  const float mu = s * (1.0f / 2048.0f);
  const float var = ss * (1.0f / 2048.0f) - mu * mu;
  const float inv = rsqrtf(var + 1e-5f);
  float o0[8];
  short8 w;
#pragma unroll
  for (int i = 0; i < 8; ++i) {
    const int c = t * 8 + i;
    o0[i] = (v[i] - mu) * inv * g[c] + bb[c];
    w[i] = f2bf(o0[i]);
  }
  float4 w0 = {o0[0], o0[1], o0[2], o0[3]}, w1 = {o0[4], o0[5], o0[6], o0[7]};
  *reinterpret_cast<float4*>(H + row * 2048 + t * 8) = w0;
  *reinterpret_cast<float4*>(H + row * 2048 + t * 8 + 4) = w1;
  *reinterpret_cast<short8*>(Hb + row * 2048 + t * 8) = w;
}

extern "C" void kernel_launch(void* const* d_in, const int* in_sizes, int n_in,
                              void* d_out, int out_size, void* d_ws, size_t ws_size,
                              hipStream_t stream) {
  const float* x    = (const float*)d_in[0];
  const float* wq   = (const float*)d_in[1];
  const float* bq   = (const float*)d_in[2];
  const float* wk   = (const float*)d_in[3];
  const float* bk   = (const float*)d_in[4];
  const float* wv   = (const float*)d_in[5];
  const float* bv   = (const float*)d_in[6];
  const float* wd   = (const float*)d_in[7];
  const float* bd   = (const float*)d_in[8];
  const float* ln_g = (const float*)d_in[9];
  const float* ln_b = (const float*)d_in[10];
  const float* w1   = (const float*)d_in[11];
  const float* b1   = (const float*)d_in[12];
  const float* w2   = (const float*)d_in[13];
  const float* b2   = (const float*)d_in[14];
  float* out = (float*)d_out;

  // ---- workspace layout (208 MiB, aliased pools) ----
  char* p = (char*)d_ws;
  ushort* wdb   = (ushort*)(p + 0);          // 8,388,608 B
  ushort* w1b   = (ushort*)(p + 8388608);    // 33,554,432
  ushort* w2b   = (ushort*)(p + 41943040);   // 33,554,432
  float*  bqkv  = (float*) (p + 75497472);   // 24,576
  ushort* xb    = (ushort*)(p + 75522048);   // poolA 16 MiB: xb -> probs
  ushort* probs = xb;
  ushort* qkv   = (ushort*)(p + 92299264);   // poolC 48 MiB: qkv -> h+hb
  float*  h     = (float*) (p + 92299264);
  ushort* hb    = (ushort*)(p + 125853696);
  ushort* wqkvb = (ushort*)(p + 142630912);  // poolB 24 MiB: wqkvb -> ctx
  ushort* ctx   = wqkvb;
  ushort* vT    = (ushort*)(p + 167796736);  // 16 MiB
  float*  scores= (float*) (p + 184573952);  // poolD 32 MiB: scores -> tres
  float*  tres  = scores;
  ushort* mlpb  = (ushort*)(p + 142630912);  // 64 MiB spanning poolB+vT+poolD

  const dim3 blk(256);
  const long SQ = (long)SEQ * SEQ;

  // ---- one-time-per-call bf16 conversions (memory-bound, ~55us) ----
  cvt8<<<4096, blk, 0, stream>>>(x, xb);
  cvt8<<<2048, blk, 0, stream>>>(wq, wqkvb);
  cvt8<<<2048, blk, 0, stream>>>(wk, wqkvb + 4194304);
  cvt8<<<2048, blk, 0, stream>>>(wv, wqkvb + 8388608);
  cvt8<<<2048, blk, 0, stream>>>(wd, wdb);
  cvt8<<<8192, blk, 0, stream>>>(w1, w1b);
  cvt8<<<8192, blk, 0, stream>>>(w2, w2b);
  concat3<<<24, blk, 0, stream>>>(bq, bk, bv, bqkv);

  // fused QKV: [4096,2048] x [6144,2048]^T -> qkv [4096][6144] bf16
  gemm_bt<EPI_QKV><<<dim3(48, 32, 1), blk, 0, stream>>>(
      xb, wqkvb, bqkv, nullptr, qkv, 6144, 2048, 2048, 2048, 6144, 0, 0, 0, 1.f);

  transpose_v<<<dim3(64, 64, 2), blk, 0, stream>>>(qkv, vT);

  // scores = q k^T / sqrt(E) per batch (q,k strided inside qkv)
  gemm_bt<EPI_SCORES><<<dim3(16, 16, 2), blk, 0, stream>>>(
      qkv, qkv + 2048, nullptr, nullptr, scores, 2048, 2048, 6144, 6144, 2048,
      2048L * 6144, 2048L * 6144, SQ, 0.022097086912079608f);

  softmax_rows<<<dim3(4096), blk, 0, stream>>>(scores, probs);

  // ctx = probs @ v
  gemm_bt<EPI_PV><<<dim3(16, 16, 2), blk, 0, stream>>>(
      probs, vT, nullptr, nullptr, ctx, 2048, 2048, 2048, 2048, 2048,
      SQ, SQ, SQ, 1.f);

  // tres = x + ctx @ wd^T + bd
  gemm_bt<EPI_RES><<<dim3(16, 32, 1), blk, 0, stream>>>(
      ctx, wdb, bd, x, tres, 2048, 2048, 2048, 2048, 2048, 0, 0, 0, 1.f);

  layernorm_rows<<<dim3(4096), blk, 0, stream>>>(tres, ln_g, ln_b, h, hb);

  // mlpb = gelu(h @ w1^T + b1)
  gemm_bt<EPI_GELU><<<dim3(64, 32, 1), blk, 0, stream>>>(
      hb, w1b, b1, nullptr, mlpb, 8192, 2048, 2048, 2048, 8192, 0, 0, 0, 1.f);

  // out = h + mlpb @ w2^T + b2
  gemm_bt<EPI_RES><<<dim3(16, 32, 1), blk, 0, stream>>>(
      mlpb, w2b, b2, h, out, 2048, 8192, 8192, 8192, 2048, 0, 0, 0, 1.f);
}

// Round 3
// 686.204 us; speedup vs baseline: 1.5861x; 1.2732x over previous
//
#include <hip/hip_runtime.h>
#include <math.h>

// PhiDecoderLayer on MI355X. B=2, S=2048, E=2048, MLP=8192, fp32 in/out.
// Round 3: 256x256 8-phase-style GEMM (4 phases per K-tile of 64, counted
// vmcnt, T2 granule-XOR LDS swizzle, setprio around MFMA clusters) for the
// four weight GEMMs; split-K=2 for the 128-block shapes; scores/PV keep the
// proven 128x128 m97-structure kernel.

#define SEQ 2048
#define EMB 2048
#define MLPD 8192

typedef __attribute__((ext_vector_type(8))) short short8;
typedef __attribute__((ext_vector_type(4))) float floatx4;
typedef unsigned short ushort;

__device__ __forceinline__ short f2bf(float f) {
  union { float f; unsigned u; } v; v.f = f;
  unsigned r = v.u + 0x7FFFu + ((v.u >> 16) & 1u);
  return (short)(r >> 16);
}

// async global->LDS, 16B per lane. LDS dest = wave-uniform base + lane*16.
__device__ __forceinline__ void gload16(const ushort* g, ushort* l) {
  __builtin_amdgcn_global_load_lds(
      (__attribute__((address_space(1))) void*)g,
      (__attribute__((address_space(3))) void*)(unsigned)(unsigned long)l,
      16, 0, 0);
}

enum { EPI_QKV = 0, EPI_SCORES = 1, EPI_PV = 2, EPI_RES = 3, EPI_GELU = 4 };

// ============================================================================
// 256x256 tile, BK=64, 8 waves (2Mx4N), per-wave 128x64 output.
// LDS 128 KiB: [buf(2)][A(32KB):half0/half1 | B(32KB):half0/half1]
// Half layout: [128 rows][64 cols bf16], 128B rows, granule-XOR swizzle:
//   LDS granule G of row r holds logical granule G ^ (r&7).
// EPI_SCORES here = raw f32 partial * scale (used for split-K partials).
// ============================================================================
template<int EPI>
__global__ __launch_bounds__(512, 2)
void gemm256(const ushort* __restrict__ A, const ushort* __restrict__ B,
             const float* __restrict__ bias, void* __restrict__ Cp,
             int N, int K, int lda, int ldb, int ldc,
             long sA, long sB, long sC, float scale)
{
  extern __shared__ ushort lds[];   // 65536 ushorts = 128 KiB
  const int t = threadIdx.x;
  const int lane = t & 63, w = t >> 6;
  const int wm = w >> 2, wn = w & 3;
  const long bm = (long)blockIdx.y * 256;
  const long bn = (long)blockIdx.x * 256;
  A += (long)blockIdx.z * sA;
  B += (long)blockIdx.z * sB;

  // ---- staging (write) geometry: pre-swizzled global source ----
  const int srow = (w << 3) + (lane >> 3);              // row within issue
  const int gcol = (lane & 7) ^ ((lane >> 3) & 7);      // swizzled granule
  const ushort* Ag = A + (bm + srow) * (long)lda + gcol * 8;
  const ushort* Bg = B + (bn + srow) * (long)ldb + gcol * 8;
  ushort* lw = lds + (w << 9);   // wave-uniform LDS base (w*1024 bytes)

#define STAGE(gb, ld, dst, kk) do {                         \
    const ushort* _g = (gb) + (kk);                         \
    gload16(_g, lw + (dst));                                \
    gload16(_g + 64L * (ld), lw + (dst) + 4096); } while (0)

  // ---- read geometry (swizzled ds_read addresses) ----
  const int l15 = lane & 15, q = lane >> 4, swz = l15 & 7;
  const int kx0 = (q ^ swz) << 3;          // ks=0 granule offset (ushorts)
  const int kx1 = ((4 + q) ^ swz) << 3;    // ks=1
  const int arow = (wm << 13) + l15 * 64;                       // A-half(wm)
  const int brow = 16384 + ((wn >> 1) << 13) + ((wn & 1) << 12) + l15 * 64;

  floatx4 acc[8][4];
#pragma unroll
  for (int m = 0; m < 8; ++m)
#pragma unroll
    for (int n = 0; n < 4; ++n) acc[m][n] = (floatx4)0.0f;

  const int NT = K >> 6;   // K-tiles of 64 (all shapes: NT >= 16, even)

  // ---- prologue: tile0 fully -> buf0, tile1 A0 -> buf1 ----
  STAGE(Ag,              lda, 0,     0);
  STAGE(Ag + 128L * lda, lda, 8192,  0);
  STAGE(Bg,              ldb, 16384, 0);
  STAGE(Bg + 128L * ldb, ldb, 24576, 0);
  STAGE(Ag,              lda, 32768, 64);
  asm volatile("s_waitcnt vmcnt(2)" ::: "memory");
  __builtin_amdgcn_s_barrier();

  for (int kt = 0; kt < NT; ++kt) {
    const int buf  = (kt & 1) ? 32768 : 0;
    const int bufn = 32768 - buf;
    const long k1 = (long)((kt + 1 < NT) ? kt + 1 : NT - 1) << 6;
    const long k2 = (long)((kt + 2 < NT) ? kt + 2 : NT - 1) << 6;
    short8 a0[4], a1[4], b0[4], b1[4];

    // ---- phase 1: read A-low + B-low ; stage A1(kt+1) ----
#pragma unroll
    for (int mf = 0; mf < 4; ++mf) {
      a0[mf] = *(const short8*)&lds[buf + arow + mf * 1024 + kx0];
      a1[mf] = *(const short8*)&lds[buf + arow + mf * 1024 + kx1];
    }
#pragma unroll
    for (int nf = 0; nf < 2; ++nf) {
      b0[nf] = *(const short8*)&lds[buf + brow + nf * 1024 + kx0];
      b1[nf] = *(const short8*)&lds[buf + brow + nf * 1024 + kx1];
    }
    STAGE(Ag + 128L * lda, lda, bufn + 8192, k1);
    __builtin_amdgcn_s_barrier();
    asm volatile("s_waitcnt lgkmcnt(0)");
    __builtin_amdgcn_s_setprio(1);
#pragma unroll
    for (int mf = 0; mf < 4; ++mf)
#pragma unroll
      for (int nf = 0; nf < 2; ++nf) {
        acc[mf][nf] = __builtin_amdgcn_mfma_f32_16x16x32_bf16(a0[mf], b0[nf], acc[mf][nf], 0, 0, 0);
        acc[mf][nf] = __builtin_amdgcn_mfma_f32_16x16x32_bf16(a1[mf], b1[nf], acc[mf][nf], 0, 0, 0);
      }
    __builtin_amdgcn_s_setprio(0);
    __builtin_amdgcn_s_barrier();

    // ---- phase 2: read B-high ; stage B0(kt+1) ----
#pragma unroll
    for (int nf = 2; nf < 4; ++nf) {
      b0[nf] = *(const short8*)&lds[buf + brow + nf * 1024 + kx0];
      b1[nf] = *(const short8*)&lds[buf + brow + nf * 1024 + kx1];
    }
    STAGE(Bg, ldb, bufn + 16384, k1);
    __builtin_amdgcn_s_barrier();
    asm volatile("s_waitcnt lgkmcnt(0)");
    __builtin_amdgcn_s_setprio(1);
#pragma unroll
    for (int mf = 0; mf < 4; ++mf)
#pragma unroll
      for (int nf = 2; nf < 4; ++nf) {
        acc[mf][nf] = __builtin_amdgcn_mfma_f32_16x16x32_bf16(a0[mf], b0[nf], acc[mf][nf], 0, 0, 0);
        acc[mf][nf] = __builtin_amdgcn_mfma_f32_16x16x32_bf16(a1[mf], b1[nf], acc[mf][nf], 0, 0, 0);
      }
    __builtin_amdgcn_s_setprio(0);
    __builtin_amdgcn_s_barrier();

    // ---- phase 3: read A-high ; stage B1(kt+1) ----
#pragma unroll
    for (int mf = 0; mf < 4; ++mf) {
      a0[mf] = *(const short8*)&lds[buf + arow + (4 + mf) * 1024 + kx0];
      a1[mf] = *(const short8*)&lds[buf + arow + (4 + mf) * 1024 + kx1];
    }
    STAGE(Bg + 128L * ldb, ldb, bufn + 24576, k1);
    __builtin_amdgcn_s_barrier();
    asm volatile("s_waitcnt lgkmcnt(0)");
    __builtin_amdgcn_s_setprio(1);
#pragma unroll
    for (int mf = 0; mf < 4; ++mf)
#pragma unroll
      for (int nf = 0; nf < 2; ++nf) {
        acc[4 + mf][nf] = __builtin_amdgcn_mfma_f32_16x16x32_bf16(a0[mf], b0[nf], acc[4 + mf][nf], 0, 0, 0);
        acc[4 + mf][nf] = __builtin_amdgcn_mfma_f32_16x16x32_bf16(a1[mf], b1[nf], acc[4 + mf][nf], 0, 0, 0);
      }
    __builtin_amdgcn_s_setprio(0);
    __builtin_amdgcn_s_barrier();

    // ---- phase 4: no reads ; stage A0(kt+2) ; group-end vmcnt(2) ----
    STAGE(Ag, lda, buf, k2);
    __builtin_amdgcn_s_barrier();
    __builtin_amdgcn_s_setprio(1);
#pragma unroll
    for (int mf = 0; mf < 4; ++mf)
#pragma unroll
      for (int nf = 2; nf < 4; ++nf) {
        acc[4 + mf][nf] = __builtin_amdgcn_mfma_f32_16x16x32_bf16(a0[mf], b0[nf], acc[4 + mf][nf], 0, 0, 0);
        acc[4 + mf][nf] = __builtin_amdgcn_mfma_f32_16x16x32_bf16(a1[mf], b1[nf], acc[4 + mf][nf], 0, 0, 0);
      }
    __builtin_amdgcn_s_setprio(0);
    asm volatile("s_waitcnt vmcnt(2)" ::: "memory");
    __builtin_amdgcn_s_barrier();
  }
#undef STAGE

  // ---- epilogue: C/D map col=lane&15, row=(lane>>4)*4+i ----
  const int lq = lane >> 4;
#pragma unroll
  for (int mf = 0; mf < 8; ++mf) {
#pragma unroll
    for (int nf = 0; nf < 4; ++nf) {
#pragma unroll
      for (int i = 0; i < 4; ++i) {
        const long r = bm + wm * 128 + mf * 16 + lq * 4 + i;
        const long c = bn + wn * 64 + nf * 16 + l15;
        float val = acc[mf][nf][i];
        if constexpr (EPI == EPI_QKV) {
          val += bias[c];
          ((ushort*)Cp)[r * (long)ldc + c] = (ushort)f2bf(val);
        } else if constexpr (EPI == EPI_SCORES) {  // raw f32 partial
          ((float*)Cp)[(long)blockIdx.z * sC + r * (long)ldc + c] = val * scale;
        } else {  // EPI_GELU exact
          val += bias[c];
          float g = 0.5f * val * (1.0f + erff(val * 0.70710678118f));
          ((ushort*)Cp)[r * (long)ldc + c] = (ushort)f2bf(g);
        }
      }
    }
  }
}

// ============================================================================
// 128x128 m97-structure kernel (proven round 2) — kept for scores & PV.
// ============================================================================
template<int EPI>
__global__ __launch_bounds__(256)
void gemm_bt(const ushort* __restrict__ A, const ushort* __restrict__ B,
             const float* __restrict__ bias, const float* __restrict__ res,
             void* __restrict__ Cp, int N, int K,
             int lda, int ldb, int ldc,
             long sA, long sB, long sC, float scale)
{
  __shared__ ushort As[128 * 32];
  __shared__ ushort Bs[128 * 32];

  const int t = threadIdx.x;
  const int lane = t & 63, wid = t >> 6;
  const int wm = wid >> 1, wn = wid & 1;
  const long bm = (long)blockIdx.y * 128;
  const long bn = (long)blockIdx.x * 128;
  A += (long)blockIdx.z * sA;
  B += (long)blockIdx.z * sB;

  const int srow = (wid << 5) + (lane >> 2);
  const int scol = (lane & 3) << 3;
  const ushort* a0 = A + (bm + srow) * (long)lda + scol;
  const ushort* a1 = a0 + 16L * lda;
  const ushort* b0 = B + (bn + srow) * (long)ldb + scol;
  const ushort* b1 = b0 + 16L * ldb;
  ushort* lA0 = As + (wid << 10);
  ushort* lA1 = lA0 + 512;
  ushort* lB0 = Bs + (wid << 10);
  ushort* lB1 = lB0 + 512;

  floatx4 acc[4][4];
#pragma unroll
  for (int m = 0; m < 4; ++m)
#pragma unroll
    for (int n = 0; n < 4; ++n) acc[m][n] = (floatx4)0.0f;

  const int l15 = lane & 15, kq = (lane >> 4) << 3;
  const int abase = ((wm << 6) + l15) * 32 + kq;
  const int bbase = ((wn << 6) + l15) * 32 + kq;

  for (int kb = 0; kb < K; kb += 32) {
    gload16(a0 + kb, lA0);
    gload16(a1 + kb, lA1);
    gload16(b0 + kb, lB0);
    gload16(b1 + kb, lB1);
    __syncthreads();

    short8 a[4], b[4];
#pragma unroll
    for (int m = 0; m < 4; ++m)
      a[m] = *reinterpret_cast<const short8*>(&As[abase + m * (16 * 32)]);
#pragma unroll
    for (int n = 0; n < 4; ++n)
      b[n] = *reinterpret_cast<const short8*>(&Bs[bbase + n * (16 * 32)]);
#pragma unroll
    for (int m = 0; m < 4; ++m)
#pragma unroll
      for (int n = 0; n < 4; ++n)
        acc[m][n] = __builtin_amdgcn_mfma_f32_16x16x32_bf16(a[m], b[n], acc[m][n], 0, 0, 0);
    __syncthreads();
  }

  const int lq = lane >> 4;
#pragma unroll
  for (int m = 0; m < 4; ++m) {
#pragma unroll
    for (int n = 0; n < 4; ++n) {
#pragma unroll
      for (int i = 0; i < 4; ++i) {
        const long r = bm + wm * 64 + m * 16 + lq * 4 + i;
        const long c = bn + wn * 64 + n * 16 + l15;
        float val = acc[m][n][i];
        if constexpr (EPI == EPI_SCORES) {
          ((float*)Cp)[(long)blockIdx.z * sC + r * (long)ldc + c] = val * scale;
        } else if constexpr (EPI == EPI_PV) {
          ((ushort*)Cp)[(long)blockIdx.z * sC + r * (long)ldc + c] = (ushort)f2bf(val);
        }
      }
    }
  }
}

// out = p0 + p1 + bias + res  (f32, 8 elems/thread, N=2048 columns)
__global__ __launch_bounds__(256)
void reduce2(const float* __restrict__ p0, const float* __restrict__ p1,
             const float* __restrict__ bias, const float* __restrict__ res,
             float* __restrict__ out)
{
  const long i = ((long)blockIdx.x * 256 + threadIdx.x) * 8;
  const int c = (int)(i & 2047);
  float4 a0 = *(const float4*)(p0 + i),  a1 = *(const float4*)(p0 + i + 4);
  float4 q0 = *(const float4*)(p1 + i),  q1 = *(const float4*)(p1 + i + 4);
  float4 r0 = *(const float4*)(res + i), r1 = *(const float4*)(res + i + 4);
  float4 b0 = *(const float4*)(bias + c), b1 = *(const float4*)(bias + c + 4);
  float4 o0 = {a0.x + q0.x + r0.x + b0.x, a0.y + q0.y + r0.y + b0.y,
               a0.z + q0.z + r0.z + b0.z, a0.w + q0.w + r0.w + b0.w};
  float4 o1 = {a1.x + q1.x + r1.x + b1.x, a1.y + q1.y + r1.y + b1.y,
               a1.z + q1.z + r1.z + b1.z, a1.w + q1.w + r1.w + b1.w};
  *(float4*)(out + i) = o0;
  *(float4*)(out + i + 4) = o1;
}

__global__ __launch_bounds__(256)
void cvt8(const float* __restrict__ s, ushort* __restrict__ d) {
  const long i = ((long)blockIdx.x * 256 + threadIdx.x) * 8;
  float4 a = *reinterpret_cast<const float4*>(s + i);
  float4 b = *reinterpret_cast<const float4*>(s + i + 4);
  short8 v;
  v[0] = f2bf(a.x); v[1] = f2bf(a.y); v[2] = f2bf(a.z); v[3] = f2bf(a.w);
  v[4] = f2bf(b.x); v[5] = f2bf(b.y); v[6] = f2bf(b.z); v[7] = f2bf(b.w);
  *reinterpret_cast<short8*>(d + i) = v;
}

__global__ __launch_bounds__(256)
void concat3(const float* __restrict__ b0, const float* __restrict__ b1,
             const float* __restrict__ b2, float* __restrict__ dst) {
  const int i = blockIdx.x * 256 + threadIdx.x;
  dst[i] = (i < 2048) ? b0[i] : (i < 4096) ? b1[i - 2048] : b2[i - 4096];
}

__global__ __launch_bounds__(256)
void transpose_v(const ushort* __restrict__ qkv, ushort* __restrict__ vT) {
  __shared__ ushort tile[32][33];
  const int b = blockIdx.z;
  const int s0 = blockIdx.x * 32, e0 = blockIdx.y * 32;
  const int tx = threadIdx.x & 31, ty = threadIdx.x >> 5;
#pragma unroll
  for (int i = 0; i < 4; ++i) {
    const long s = (long)b * SEQ + s0 + ty + i * 8;
    tile[ty + i * 8][tx] = qkv[s * 6144 + 4096 + e0 + tx];
  }
  __syncthreads();
#pragma unroll
  for (int i = 0; i < 4; ++i) {
    const long e = (long)b * SEQ + e0 + ty + i * 8;
    vT[e * SEQ + s0 + tx] = tile[tx][ty + i * 8];
  }
}

__global__ __launch_bounds__(256)
void softmax_rows(const float* __restrict__ S, ushort* __restrict__ P) {
  const long row = blockIdx.x;
  const float* src = S + row * 2048;
  const int t = threadIdx.x, lane = t & 63, wid = t >> 6;
  float4 a = *reinterpret_cast<const float4*>(src + t * 8);
  float4 b = *reinterpret_cast<const float4*>(src + t * 8 + 4);
  float v[8] = {a.x, a.y, a.z, a.w, b.x, b.y, b.z, b.w};
  float m = v[0];
#pragma unroll
  for (int i = 1; i < 8; ++i) m = fmaxf(m, v[i]);
#pragma unroll
  for (int o = 32; o; o >>= 1) m = fmaxf(m, __shfl_xor(m, o));
  __shared__ float rm[4], rs[4];
  if (!lane) rm[wid] = m;
  __syncthreads();
  m = fmaxf(fmaxf(rm[0], rm[1]), fmaxf(rm[2], rm[3]));
  float e[8], s = 0.f;
#pragma unroll
  for (int i = 0; i < 8; ++i) { e[i] = __expf(v[i] - m); s += e[i]; }
#pragma unroll
  for (int o = 32; o; o >>= 1) s += __shfl_xor(s, o);
  if (!lane) rs[wid] = s;
  __syncthreads();
  s = rs[0] + rs[1] + rs[2] + rs[3];
  const float inv = 1.0f / s;
  short8 wv;
#pragma unroll
  for (int i = 0; i < 8; ++i) wv[i] = f2bf(e[i] * inv);
  *reinterpret_cast<short8*>(P + row * 2048 + t * 8) = wv;
}

__global__ __launch_bounds__(256)
void layernorm_rows(const float* __restrict__ X, const float* __restrict__ g,
                    const float* __restrict__ bb, float* __restrict__ H,
                    ushort* __restrict__ Hb) {
  const long row = blockIdx.x;
  const float* src = X + row * 2048;
  const int t = threadIdx.x, lane = t & 63, wid = t >> 6;
  float4 a = *reinterpret_cast<const float4*>(src + t * 8);
  float4 b = *reinterpret_cast<const float4*>(src + t * 8 + 4);
  float v[8] = {a.x, a.y, a.z, a.w, b.x, b.y, b.z, b.w};
  float s = 0.f, ss = 0.f;
#pragma unroll
  for (int i = 0; i < 8; ++i) { s += v[i]; ss += v[i] * v[i]; }
#pragma unroll
  for (int o = 32; o; o >>= 1) { s += __shfl_xor(s, o); ss += __shfl_xor(ss, o); }
  __shared__ float r1[4], r2[4];
  if (!lane) { r1[wid] = s; r2[wid] = ss; }
  __syncthreads();
  s = r1[0] + r1[1] + r1[2] + r1[3];
  ss = r2[0] + r2[1] + r2[2] + r2[3];
  const float mu = s * (1.0f / 2048.0f);
  const float var = ss * (1.0f / 2048.0f) - mu * mu;
  const float inv = rsqrtf(var + 1e-5f);
  float o0[8];
  short8 wv;
#pragma unroll
  for (int i = 0; i < 8; ++i) {
    const int c = t * 8 + i;
    o0[i] = (v[i] - mu) * inv * g[c] + bb[c];
    wv[i] = f2bf(o0[i]);
  }
  float4 w0 = {o0[0], o0[1], o0[2], o0[3]}, w1 = {o0[4], o0[5], o0[6], o0[7]};
  *reinterpret_cast<float4*>(H + row * 2048 + t * 8) = w0;
  *reinterpret_cast<float4*>(H + row * 2048 + t * 8 + 4) = w1;
  *reinterpret_cast<short8*>(Hb + row * 2048 + t * 8) = wv;
}

extern "C" void kernel_launch(void* const* d_in, const int* in_sizes, int n_in,
                              void* d_out, int out_size, void* d_ws, size_t ws_size,
                              hipStream_t stream) {
  const float* x    = (const float*)d_in[0];
  const float* wq   = (const float*)d_in[1];
  const float* bq   = (const float*)d_in[2];
  const float* wk   = (const float*)d_in[3];
  const float* bk   = (const float*)d_in[4];
  const float* wv   = (const float*)d_in[5];
  const float* bv   = (const float*)d_in[6];
  const float* wd   = (const float*)d_in[7];
  const float* bd   = (const float*)d_in[8];
  const float* ln_g = (const float*)d_in[9];
  const float* ln_b = (const float*)d_in[10];
  const float* w1   = (const float*)d_in[11];
  const float* b1   = (const float*)d_in[12];
  const float* w2   = (const float*)d_in[13];
  const float* b2   = (const float*)d_in[14];
  float* out = (float*)d_out;

  // opt-in to 128 KiB dynamic LDS (no-op if already allowed)
  (void)hipFuncSetAttribute((const void*)&gemm256<EPI_QKV>,
      hipFuncAttributeMaxDynamicSharedMemorySize, 131072);
  (void)hipFuncSetAttribute((const void*)&gemm256<EPI_GELU>,
      hipFuncAttributeMaxDynamicSharedMemorySize, 131072);
  (void)hipFuncSetAttribute((const void*)&gemm256<EPI_SCORES>,
      hipFuncAttributeMaxDynamicSharedMemorySize, 131072);

  // ---- workspace layout (233 MiB, aliased; see timeline in comments) ----
  char* p = (char*)d_ws;
  const size_t MB = 1048576;
  ushort* wdb    = (ushort*)(p + 0 * MB);     // 8 MB   [dead after attn-out]
  ushort* w1b    = (ushort*)(p + 8 * MB);     // 32 MB  [dead after mlp1]
  ushort* w2b    = (ushort*)(p + 40 * MB);    // 32 MB  [live till mlp2]
  float*  bqkv   = (float*) (p + 72 * MB);    // 24 KB
  ushort* xb     = (ushort*)(p + 73 * MB);    // 16 MB  -> probs
  ushort* probs  = xb;
  ushort* qkv    = (ushort*)(p + 89 * MB);    // 48 MB  -> partA -> mlpb
  float*  partA  = (float*) (p + 89 * MB);    // 64 MB (z-stride 32 MB)
  ushort* mlpb   = (ushort*)(p + 89 * MB);    // 64 MB
  ushort* vT     = (ushort*)(p + 137 * MB);   // 16 MB  [dead after PV]
  ushort* wqkvb  = (ushort*)(p + 153 * MB);   // 24 MB  [dead after QKV]
  float*  scores = (float*) (p + 153 * MB);   // 32 MB  [dead after softmax]
  ushort* ctx    = (ushort*)(p + 153 * MB);   // 16 MB  [dead after attn-out]
  float*  tres   = (float*) (p + 153 * MB);   // 32 MB  [dead after LN]
  float*  partM0 = (float*) (p + 0 * MB);     // 32 MB  (wdb/w1b dead by mlp2)
  // partM z=1 lives at 153 MB: sC = 153*MB/4 floats
  float*  h      = (float*) (p + 185 * MB);   // 32 MB  [live till end]
  ushort* hb     = (ushort*)(p + 217 * MB);   // 16 MB  [dead after mlp1]

  const dim3 blk(256), blk512(512);
  const long SQ = (long)SEQ * SEQ;

  // ---- bf16 conversions ----
  cvt8<<<4096, blk, 0, stream>>>(x, xb);
  cvt8<<<2048, blk, 0, stream>>>(wq, wqkvb);
  cvt8<<<2048, blk, 0, stream>>>(wk, wqkvb + 4194304);
  cvt8<<<2048, blk, 0, stream>>>(wv, wqkvb + 8388608);
  cvt8<<<2048, blk, 0, stream>>>(wd, wdb);
  cvt8<<<8192, blk, 0, stream>>>(w1, w1b);
  cvt8<<<8192, blk, 0, stream>>>(w2, w2b);
  concat3<<<24, blk, 0, stream>>>(bq, bk, bv, bqkv);

  // fused QKV: [4096,2048] x [6144,2048]^T -> qkv bf16 [4096][6144]
  gemm256<EPI_QKV><<<dim3(24, 16, 1), blk512, 131072, stream>>>(
      xb, wqkvb, bqkv, qkv, 6144, 2048, 2048, 2048, 6144, 0, 0, 0, 1.f);

  transpose_v<<<dim3(64, 64, 2), blk, 0, stream>>>(qkv, vT);

  // scores = q k^T / sqrt(E), per batch (128x128 kernel, full-util grid)
  gemm_bt<EPI_SCORES><<<dim3(16, 16, 2), blk, 0, stream>>>(
      qkv, qkv + 2048, nullptr, nullptr, scores, 2048, 2048, 6144, 6144, 2048,
      2048L * 6144, 2048L * 6144, SQ, 0.022097086912079608f);

  softmax_rows<<<dim3(4096), blk, 0, stream>>>(scores, probs);

  // ctx = probs @ v
  gemm_bt<EPI_PV><<<dim3(16, 16, 2), blk, 0, stream>>>(
      probs, vT, nullptr, nullptr, ctx, 2048, 2048, 2048, 2048, 2048,
      SQ, SQ, SQ, 1.f);

  // attn-out, split-K=2: partA[z] = ctx[:, z*1024:+1024] @ wd^T-slice
  gemm256<EPI_SCORES><<<dim3(8, 16, 2), blk512, 131072, stream>>>(
      ctx, wdb, nullptr, partA, 2048, 1024, 2048, 2048, 2048,
      1024, 1024, 8388608, 1.f);
  // tres = partA0 + partA1 + bd + x
  reduce2<<<4096, blk, 0, stream>>>(partA, partA + 8388608, bd, x, tres);

  layernorm_rows<<<4096, blk, 0, stream>>>(tres, ln_g, ln_b, h, hb);

  // mlpb = gelu(h @ w1^T + b1)
  gemm256<EPI_GELU><<<dim3(32, 16, 1), blk512, 131072, stream>>>(
      hb, w1b, b1, mlpb, 8192, 2048, 2048, 2048, 8192, 0, 0, 0, 1.f);

  // mlp2, split-K=2: partM[z] = mlpb[:, z*4096:+4096] @ w2^T-slice
  gemm256<EPI_SCORES><<<dim3(8, 16, 2), blk512, 131072, stream>>>(
      mlpb, w2b, nullptr, partM0, 2048, 4096, 8192, 8192, 2048,
      4096, 4096, (long)(153 * MB / 4), 1.f);
  // out = partM0 + partM1 + b2 + h
  reduce2<<<4096, blk, 0, stream>>>(partM0, (float*)(p + 153 * MB), b2, h, out);
}

// Round 4
// 672.960 us; speedup vs baseline: 1.6173x; 1.0197x over previous
//
#include <hip/hip_runtime.h>
#include <math.h>

// PhiDecoderLayer on MI355X. B=2, S=2048, E=2048, MLP=8192, fp32 in/out.
// Round 4: gemm256 pipeline rebuilt lag-maximal: A-halves of tile kt+1
// staged at kt.ph1/ph2, B-halves of tile kt+2 at kt.ph3/ph4, single
// vmcnt(4) per K-tile (min 2.5-phase latency cover). + XCD chunked swizzle,
// + attn residual reduce fused into LayerNorm.

#define SEQ 2048
#define EMB 2048
#define MLPD 8192

typedef __attribute__((ext_vector_type(8))) short short8;
typedef __attribute__((ext_vector_type(4))) float floatx4;
typedef unsigned short ushort;

__device__ __forceinline__ short f2bf(float f) {
  union { float f; unsigned u; } v; v.f = f;
  unsigned r = v.u + 0x7FFFu + ((v.u >> 16) & 1u);
  return (short)(r >> 16);
}

// async global->LDS, 16B per lane. LDS dest = wave-uniform base + lane*16.
__device__ __forceinline__ void gload16(const ushort* g, ushort* l) {
  __builtin_amdgcn_global_load_lds(
      (__attribute__((address_space(1))) void*)g,
      (__attribute__((address_space(3))) void*)(unsigned)(unsigned long)l,
      16, 0, 0);
}

enum { EPI_QKV = 0, EPI_SCORES = 1, EPI_PV = 2, EPI_RES = 3, EPI_GELU = 4 };

// ============================================================================
// 256x256 tile, BK=64, 8 waves (2Mx4N), per-wave 128x64 output.
// LDS 128 KiB: [buf(2)][A0|A1|B0|B1 half-tiles of 128rows x 64cols]
// granule-XOR swizzle: LDS granule G of row r holds logical granule G^(r&7).
// Schedule per K-tile kt (4 phases):
//  ph1: read A-low+B-low(cur); STAGE A0(kt+1)->nxt; bar; lgkm0; 16 MFMA; bar
//  ph2: read B-high(cur);      STAGE A1(kt+1)->nxt; bar; lgkm0; 16 MFMA; bar
//  ph3: read A-high(cur);      STAGE B0(kt+2)->cur; bar; lgkm0; 16 MFMA; bar
//  ph4:                        STAGE B1(kt+2)->cur; 16 MFMA; vmcnt(4); bar
// vmcnt(4) drains everything needed for tile kt+1 (issue-order arithmetic:
// queue = B0/B1(kt+1)@kt-1.ph3/4, A0/A1(kt+1)@kt.ph1/2, B0/B1(kt+2)@kt.ph3/4).
// ============================================================================
template<int EPI>
__global__ __launch_bounds__(512, 2)
void gemm256(const ushort* __restrict__ A, const ushort* __restrict__ B,
             const float* __restrict__ bias, void* __restrict__ Cp,
             int N, int K, int lda, int ldb, int ldc,
             long sA, long sB, long sC, float scale)
{
  extern __shared__ ushort lds[];   // 65536 ushorts = 128 KiB
  const int t = threadIdx.x;
  const int lane = t & 63, w = t >> 6;
  const int wm = w >> 2, wn = w & 3;

  // XCD chunked swizzle (nwg divisible by 8): consecutive works share bx.
  const int gx = gridDim.x, gy = gridDim.y;
  const int bid = blockIdx.y * gx + blockIdx.x;
  const int cpx = (gx * gy) >> 3;
  const int work = (bid & 7) * cpx + (bid >> 3);
  const long bm = (long)(work % gy) * 256;
  const long bn = (long)(work / gy) * 256;
  A += (long)blockIdx.z * sA;
  B += (long)blockIdx.z * sB;

  // ---- staging (write) geometry: pre-swizzled global source ----
  const int srow = (w << 3) + (lane >> 3);              // row within issue
  const int gcol = (lane & 7) ^ ((lane >> 3) & 7);      // swizzled granule
  const ushort* Ag = A + (bm + srow) * (long)lda + gcol * 8;
  const ushort* Bg = B + (bn + srow) * (long)ldb + gcol * 8;
  ushort* lw = lds + (w << 9);   // wave-uniform LDS base (w*1024 bytes)

#define STAGE(gb, ld, dst, kk) do {                         \
    const ushort* _g = (gb) + (kk);                         \
    gload16(_g, lw + (dst));                                \
    gload16(_g + 64L * (ld), lw + (dst) + 4096); } while (0)

  // ---- read geometry (swizzled ds_read addresses) ----
  const int l15 = lane & 15, q = lane >> 4, swz = l15 & 7;
  const int kx0 = (q ^ swz) << 3;          // ks=0 granule offset (ushorts)
  const int kx1 = ((4 + q) ^ swz) << 3;    // ks=1
  const int arow = (wm << 13) + l15 * 64;                       // A-half(wm)
  const int brow = 16384 + ((wn >> 1) << 13) + ((wn & 1) << 12) + l15 * 64;

  floatx4 acc[8][4];
#pragma unroll
  for (int m = 0; m < 8; ++m)
#pragma unroll
    for (int n = 0; n < 4; ++n) acc[m][n] = (floatx4)0.0f;

  const int NT = K >> 6;   // K-tiles of 64

  // ---- prologue: tile0 -> buf0; B-halves of tile1 -> buf1 ----
  STAGE(Ag,              lda, 0,     0);
  STAGE(Ag + 128L * lda, lda, 8192,  0);
  STAGE(Bg,              ldb, 16384, 0);
  STAGE(Bg + 128L * ldb, ldb, 24576, 0);
  {
    const long k1p = (NT > 1) ? 64 : 0;
    STAGE(Bg,              ldb, 32768 + 16384, k1p);
    STAGE(Bg + 128L * ldb, ldb, 32768 + 24576, k1p);
  }
  asm volatile("s_waitcnt vmcnt(4)" ::: "memory");
  __builtin_amdgcn_s_barrier();

  for (int kt = 0; kt < NT; ++kt) {
    const int cur = (kt & 1) ? 32768 : 0;
    const int nxt = 32768 - cur;
    const long k1 = (long)((kt + 1 < NT) ? kt + 1 : NT - 1) << 6;
    const long k2 = (long)((kt + 2 < NT) ? kt + 2 : NT - 1) << 6;
    short8 a0[4], a1[4], b0[4], b1[4];

    // ---- phase 1: read A-low + B-low ; stage A0(kt+1) -> nxt ----
#pragma unroll
    for (int mf = 0; mf < 4; ++mf) {
      a0[mf] = *(const short8*)&lds[cur + arow + mf * 1024 + kx0];
      a1[mf] = *(const short8*)&lds[cur + arow + mf * 1024 + kx1];
    }
#pragma unroll
    for (int nf = 0; nf < 2; ++nf) {
      b0[nf] = *(const short8*)&lds[cur + brow + nf * 1024 + kx0];
      b1[nf] = *(const short8*)&lds[cur + brow + nf * 1024 + kx1];
    }
    STAGE(Ag, lda, nxt, k1);
    __builtin_amdgcn_s_barrier();
    asm volatile("s_waitcnt lgkmcnt(0)");
    __builtin_amdgcn_s_setprio(1);
#pragma unroll
    for (int mf = 0; mf < 4; ++mf)
#pragma unroll
      for (int nf = 0; nf < 2; ++nf) {
        acc[mf][nf] = __builtin_amdgcn_mfma_f32_16x16x32_bf16(a0[mf], b0[nf], acc[mf][nf], 0, 0, 0);
        acc[mf][nf] = __builtin_amdgcn_mfma_f32_16x16x32_bf16(a1[mf], b1[nf], acc[mf][nf], 0, 0, 0);
      }
    __builtin_amdgcn_s_setprio(0);
    __builtin_amdgcn_s_barrier();

    // ---- phase 2: read B-high ; stage A1(kt+1) -> nxt ----
#pragma unroll
    for (int nf = 2; nf < 4; ++nf) {
      b0[nf] = *(const short8*)&lds[cur + brow + nf * 1024 + kx0];
      b1[nf] = *(const short8*)&lds[cur + brow + nf * 1024 + kx1];
    }
    STAGE(Ag + 128L * lda, lda, nxt + 8192, k1);
    __builtin_amdgcn_s_barrier();
    asm volatile("s_waitcnt lgkmcnt(0)");
    __builtin_amdgcn_s_setprio(1);
#pragma unroll
    for (int mf = 0; mf < 4; ++mf)
#pragma unroll
      for (int nf = 2; nf < 4; ++nf) {
        acc[mf][nf] = __builtin_amdgcn_mfma_f32_16x16x32_bf16(a0[mf], b0[nf], acc[mf][nf], 0, 0, 0);
        acc[mf][nf] = __builtin_amdgcn_mfma_f32_16x16x32_bf16(a1[mf], b1[nf], acc[mf][nf], 0, 0, 0);
      }
    __builtin_amdgcn_s_setprio(0);
    __builtin_amdgcn_s_barrier();

    // ---- phase 3: read A-high ; stage B0(kt+2) -> cur (B region dead) ----
#pragma unroll
    for (int mf = 0; mf < 4; ++mf) {
      a0[mf] = *(const short8*)&lds[cur + arow + (4 + mf) * 1024 + kx0];
      a1[mf] = *(const short8*)&lds[cur + arow + (4 + mf) * 1024 + kx1];
    }
    STAGE(Bg, ldb, cur + 16384, k2);
    __builtin_amdgcn_s_barrier();
    asm volatile("s_waitcnt lgkmcnt(0)");
    __builtin_amdgcn_s_setprio(1);
#pragma unroll
    for (int mf = 0; mf < 4; ++mf)
#pragma unroll
      for (int nf = 0; nf < 2; ++nf) {
        acc[4 + mf][nf] = __builtin_amdgcn_mfma_f32_16x16x32_bf16(a0[mf], b0[nf], acc[4 + mf][nf], 0, 0, 0);
        acc[4 + mf][nf] = __builtin_amdgcn_mfma_f32_16x16x32_bf16(a1[mf], b1[nf], acc[4 + mf][nf], 0, 0, 0);
      }
    __builtin_amdgcn_s_setprio(0);
    __builtin_amdgcn_s_barrier();

    // ---- phase 4: stage B1(kt+2) -> cur ; MFMA ; vmcnt(4) ; barrier ----
    STAGE(Bg + 128L * ldb, ldb, cur + 24576, k2);
    __builtin_amdgcn_s_setprio(1);
#pragma unroll
    for (int mf = 0; mf < 4; ++mf)
#pragma unroll
      for (int nf = 2; nf < 4; ++nf) {
        acc[4 + mf][nf] = __builtin_amdgcn_mfma_f32_16x16x32_bf16(a0[mf], b0[nf], acc[4 + mf][nf], 0, 0, 0);
        acc[4 + mf][nf] = __builtin_amdgcn_mfma_f32_16x16x32_bf16(a1[mf], b1[nf], acc[4 + mf][nf], 0, 0, 0);
      }
    __builtin_amdgcn_s_setprio(0);
    asm volatile("s_waitcnt vmcnt(4)" ::: "memory");
    __builtin_amdgcn_s_barrier();
  }
#undef STAGE

  // ---- epilogue: C/D map col=lane&15, row=(lane>>4)*4+i ----
  const int lq = lane >> 4;
#pragma unroll
  for (int mf = 0; mf < 8; ++mf) {
#pragma unroll
    for (int nf = 0; nf < 4; ++nf) {
#pragma unroll
      for (int i = 0; i < 4; ++i) {
        const long r = bm + wm * 128 + mf * 16 + lq * 4 + i;
        const long c = bn + wn * 64 + nf * 16 + l15;
        float val = acc[mf][nf][i];
        if constexpr (EPI == EPI_QKV) {
          val += bias[c];
          ((ushort*)Cp)[r * (long)ldc + c] = (ushort)f2bf(val);
        } else if constexpr (EPI == EPI_SCORES) {  // raw f32 partial
          ((float*)Cp)[(long)blockIdx.z * sC + r * (long)ldc + c] = val * scale;
        } else {  // EPI_GELU exact
          val += bias[c];
          float g = 0.5f * val * (1.0f + erff(val * 0.70710678118f));
          ((ushort*)Cp)[r * (long)ldc + c] = (ushort)f2bf(g);
        }
      }
    }
  }
}

// ============================================================================
// 128x128 m97-structure kernel — kept for scores & PV (512-block grids).
// ============================================================================
template<int EPI>
__global__ __launch_bounds__(256)
void gemm_bt(const ushort* __restrict__ A, const ushort* __restrict__ B,
             const float* __restrict__ bias, const float* __restrict__ res,
             void* __restrict__ Cp, int N, int K,
             int lda, int ldb, int ldc,
             long sA, long sB, long sC, float scale)
{
  __shared__ ushort As[128 * 32];
  __shared__ ushort Bs[128 * 32];

  const int t = threadIdx.x;
  const int lane = t & 63, wid = t >> 6;
  const int wm = wid >> 1, wn = wid & 1;
  const long bm = (long)blockIdx.y * 128;
  const long bn = (long)blockIdx.x * 128;
  A += (long)blockIdx.z * sA;
  B += (long)blockIdx.z * sB;

  const int srow = (wid << 5) + (lane >> 2);
  const int scol = (lane & 3) << 3;
  const ushort* a0 = A + (bm + srow) * (long)lda + scol;
  const ushort* a1 = a0 + 16L * lda;
  const ushort* b0 = B + (bn + srow) * (long)ldb + scol;
  const ushort* b1 = b0 + 16L * ldb;
  ushort* lA0 = As + (wid << 10);
  ushort* lA1 = lA0 + 512;
  ushort* lB0 = Bs + (wid << 10);
  ushort* lB1 = lB0 + 512;

  floatx4 acc[4][4];
#pragma unroll
  for (int m = 0; m < 4; ++m)
#pragma unroll
    for (int n = 0; n < 4; ++n) acc[m][n] = (floatx4)0.0f;

  const int l15 = lane & 15, kq = (lane >> 4) << 3;
  const int abase = ((wm << 6) + l15) * 32 + kq;
  const int bbase = ((wn << 6) + l15) * 32 + kq;

  for (int kb = 0; kb < K; kb += 32) {
    gload16(a0 + kb, lA0);
    gload16(a1 + kb, lA1);
    gload16(b0 + kb, lB0);
    gload16(b1 + kb, lB1);
    __syncthreads();

    short8 a[4], b[4];
#pragma unroll
    for (int m = 0; m < 4; ++m)
      a[m] = *reinterpret_cast<const short8*>(&As[abase + m * (16 * 32)]);
#pragma unroll
    for (int n = 0; n < 4; ++n)
      b[n] = *reinterpret_cast<const short8*>(&Bs[bbase + n * (16 * 32)]);
#pragma unroll
    for (int m = 0; m < 4; ++m)
#pragma unroll
      for (int n = 0; n < 4; ++n)
        acc[m][n] = __builtin_amdgcn_mfma_f32_16x16x32_bf16(a[m], b[n], acc[m][n], 0, 0, 0);
    __syncthreads();
  }

  const int lq = lane >> 4;
#pragma unroll
  for (int m = 0; m < 4; ++m) {
#pragma unroll
    for (int n = 0; n < 4; ++n) {
#pragma unroll
      for (int i = 0; i < 4; ++i) {
        const long r = bm + wm * 64 + m * 16 + lq * 4 + i;
        const long c = bn + wn * 64 + n * 16 + l15;
        float val = acc[m][n][i];
        if constexpr (EPI == EPI_SCORES) {
          ((float*)Cp)[(long)blockIdx.z * sC + r * (long)ldc + c] = val * scale;
        } else if constexpr (EPI == EPI_PV) {
          ((ushort*)Cp)[(long)blockIdx.z * sC + r * (long)ldc + c] = (ushort)f2bf(val);
        }
      }
    }
  }
}

// out = p0 + p1 + bias + res  (f32, 8 elems/thread, N=2048 columns)
__global__ __launch_bounds__(256)
void reduce2(const float* __restrict__ p0, const float* __restrict__ p1,
             const float* __restrict__ bias, const float* __restrict__ res,
             float* __restrict__ out)
{
  const long i = ((long)blockIdx.x * 256 + threadIdx.x) * 8;
  const int c = (int)(i & 2047);
  float4 a0 = *(const float4*)(p0 + i),  a1 = *(const float4*)(p0 + i + 4);
  float4 q0 = *(const float4*)(p1 + i),  q1 = *(const float4*)(p1 + i + 4);
  float4 r0 = *(const float4*)(res + i), r1 = *(const float4*)(res + i + 4);
  float4 b0 = *(const float4*)(bias + c), b1 = *(const float4*)(bias + c + 4);
  float4 o0 = {a0.x + q0.x + r0.x + b0.x, a0.y + q0.y + r0.y + b0.y,
               a0.z + q0.z + r0.z + b0.z, a0.w + q0.w + r0.w + b0.w};
  float4 o1 = {a1.x + q1.x + r1.x + b1.x, a1.y + q1.y + r1.y + b1.y,
               a1.z + q1.z + r1.z + b1.z, a1.w + q1.w + r1.w + b1.w};
  *(float4*)(out + i) = o0;
  *(float4*)(out + i + 4) = o1;
}

__global__ __launch_bounds__(256)
void cvt8(const float* __restrict__ s, ushort* __restrict__ d) {
  const long i = ((long)blockIdx.x * 256 + threadIdx.x) * 8;
  float4 a = *reinterpret_cast<const float4*>(s + i);
  float4 b = *reinterpret_cast<const float4*>(s + i + 4);
  short8 v;
  v[0] = f2bf(a.x); v[1] = f2bf(a.y); v[2] = f2bf(a.z); v[3] = f2bf(a.w);
  v[4] = f2bf(b.x); v[5] = f2bf(b.y); v[6] = f2bf(b.z); v[7] = f2bf(b.w);
  *reinterpret_cast<short8*>(d + i) = v;
}

__global__ __launch_bounds__(256)
void concat3(const float* __restrict__ b0, const float* __restrict__ b1,
             const float* __restrict__ b2, float* __restrict__ dst) {
  const int i = blockIdx.x * 256 + threadIdx.x;
  dst[i] = (i < 2048) ? b0[i] : (i < 4096) ? b1[i - 2048] : b2[i - 4096];
}

__global__ __launch_bounds__(256)
void transpose_v(const ushort* __restrict__ qkv, ushort* __restrict__ vT) {
  __shared__ ushort tile[32][33];
  const int b = blockIdx.z;
  const int s0 = blockIdx.x * 32, e0 = blockIdx.y * 32;
  const int tx = threadIdx.x & 31, ty = threadIdx.x >> 5;
#pragma unroll
  for (int i = 0; i < 4; ++i) {
    const long s = (long)b * SEQ + s0 + ty + i * 8;
    tile[ty + i * 8][tx] = qkv[s * 6144 + 4096 + e0 + tx];
  }
  __syncthreads();
#pragma unroll
  for (int i = 0; i < 4; ++i) {
    const long e = (long)b * SEQ + e0 + ty + i * 8;
    vT[e * SEQ + s0 + tx] = tile[tx][ty + i * 8];
  }
}

__global__ __launch_bounds__(256)
void softmax_rows(const float* __restrict__ S, ushort* __restrict__ P) {
  const long row = blockIdx.x;
  const float* src = S + row * 2048;
  const int t = threadIdx.x, lane = t & 63, wid = t >> 6;
  float4 a = *reinterpret_cast<const float4*>(src + t * 8);
  float4 b = *reinterpret_cast<const float4*>(src + t * 8 + 4);
  float v[8] = {a.x, a.y, a.z, a.w, b.x, b.y, b.z, b.w};
  float m = v[0];
#pragma unroll
  for (int i = 1; i < 8; ++i) m = fmaxf(m, v[i]);
#pragma unroll
  for (int o = 32; o; o >>= 1) m = fmaxf(m, __shfl_xor(m, o));
  __shared__ float rm[4], rs[4];
  if (!lane) rm[wid] = m;
  __syncthreads();
  m = fmaxf(fmaxf(rm[0], rm[1]), fmaxf(rm[2], rm[3]));
  float e[8], s = 0.f;
#pragma unroll
  for (int i = 0; i < 8; ++i) { e[i] = __expf(v[i] - m); s += e[i]; }
#pragma unroll
  for (int o = 32; o; o >>= 1) s += __shfl_xor(s, o);
  if (!lane) rs[wid] = s;
  __syncthreads();
  s = rs[0] + rs[1] + rs[2] + rs[3];
  const float inv = 1.0f / s;
  short8 wv;
#pragma unroll
  for (int i = 0; i < 8; ++i) wv[i] = f2bf(e[i] * inv);
  *reinterpret_cast<short8*>(P + row * 2048 + t * 8) = wv;
}

// layernorm of (p0 + p1 + bias + res), emitting f32 H and bf16 Hb.
__global__ __launch_bounds__(256)
void layernorm_fused(const float* __restrict__ p0, const float* __restrict__ p1,
                     const float* __restrict__ bias, const float* __restrict__ res,
                     const float* __restrict__ g, const float* __restrict__ bb,
                     float* __restrict__ H, ushort* __restrict__ Hb) {
  const long row = blockIdx.x;
  const long base = row * 2048;
  const int t = threadIdx.x, lane = t & 63, wid = t >> 6;
  const long i = base + t * 8;
  const int c0 = t * 8;
  float v[8];
  {
    float4 a0 = *(const float4*)(p0 + i),  a1 = *(const float4*)(p0 + i + 4);
    float4 q0 = *(const float4*)(p1 + i),  q1 = *(const float4*)(p1 + i + 4);
    float4 r0 = *(const float4*)(res + i), r1 = *(const float4*)(res + i + 4);
    float4 b0 = *(const float4*)(bias + c0), b1 = *(const float4*)(bias + c0 + 4);
    v[0] = a0.x + q0.x + r0.x + b0.x; v[1] = a0.y + q0.y + r0.y + b0.y;
    v[2] = a0.z + q0.z + r0.z + b0.z; v[3] = a0.w + q0.w + r0.w + b0.w;
    v[4] = a1.x + q1.x + r1.x + b1.x; v[5] = a1.y + q1.y + r1.y + b1.y;
    v[6] = a1.z + q1.z + r1.z + b1.z; v[7] = a1.w + q1.w + r1.w + b1.w;
  }
  float s = 0.f, ss = 0.f;
#pragma unroll
  for (int i2 = 0; i2 < 8; ++i2) { s += v[i2]; ss += v[i2] * v[i2]; }
#pragma unroll
  for (int o = 32; o; o >>= 1) { s += __shfl_xor(s, o); ss += __shfl_xor(ss, o); }
  __shared__ float r1s[4], r2s[4];
  if (!lane) { r1s[wid] = s; r2s[wid] = ss; }
  __syncthreads();
  s = r1s[0] + r1s[1] + r1s[2] + r1s[3];
  ss = r2s[0] + r2s[1] + r2s[2] + r2s[3];
  const float mu = s * (1.0f / 2048.0f);
  const float var = ss * (1.0f / 2048.0f) - mu * mu;
  const float inv = rsqrtf(var + 1e-5f);
  float o0[8];
  short8 wv;
#pragma unroll
  for (int i2 = 0; i2 < 8; ++i2) {
    const int c = c0 + i2;
    o0[i2] = (v[i2] - mu) * inv * g[c] + bb[c];
    wv[i2] = f2bf(o0[i2]);
  }
  float4 w0 = {o0[0], o0[1], o0[2], o0[3]}, w1 = {o0[4], o0[5], o0[6], o0[7]};
  *reinterpret_cast<float4*>(H + i) = w0;
  *reinterpret_cast<float4*>(H + i + 4) = w1;
  *reinterpret_cast<short8*>(Hb + i) = wv;
}

extern "C" void kernel_launch(void* const* d_in, const int* in_sizes, int n_in,
                              void* d_out, int out_size, void* d_ws, size_t ws_size,
                              hipStream_t stream) {
  const float* x    = (const float*)d_in[0];
  const float* wq   = (const float*)d_in[1];
  const float* bq   = (const float*)d_in[2];
  const float* wk   = (const float*)d_in[3];
  const float* bk   = (const float*)d_in[4];
  const float* wv   = (const float*)d_in[5];
  const float* bv   = (const float*)d_in[6];
  const float* wd   = (const float*)d_in[7];
  const float* bd   = (const float*)d_in[8];
  const float* ln_g = (const float*)d_in[9];
  const float* ln_b = (const float*)d_in[10];
  const float* w1   = (const float*)d_in[11];
  const float* b1   = (const float*)d_in[12];
  const float* w2   = (const float*)d_in[13];
  const float* b2   = (const float*)d_in[14];
  float* out = (float*)d_out;

  (void)hipFuncSetAttribute((const void*)&gemm256<EPI_QKV>,
      hipFuncAttributeMaxDynamicSharedMemorySize, 131072);
  (void)hipFuncSetAttribute((const void*)&gemm256<EPI_GELU>,
      hipFuncAttributeMaxDynamicSharedMemorySize, 131072);
  (void)hipFuncSetAttribute((const void*)&gemm256<EPI_SCORES>,
      hipFuncAttributeMaxDynamicSharedMemorySize, 131072);

  // ---- workspace layout (233 MiB, aliased) ----
  char* p = (char*)d_ws;
  const size_t MB = 1048576;
  ushort* wdb    = (ushort*)(p + 0 * MB);     // 8 MB   [dead after attn-out]
  ushort* w1b    = (ushort*)(p + 8 * MB);     // 32 MB  [dead after mlp1]
  ushort* w2b    = (ushort*)(p + 40 * MB);    // 32 MB  [live till mlp2]
  float*  bqkv   = (float*) (p + 72 * MB);    // 24 KB
  ushort* xb     = (ushort*)(p + 73 * MB);    // 16 MB  -> probs
  ushort* probs  = xb;
  ushort* qkv    = (ushort*)(p + 89 * MB);    // 48 MB  -> partA -> mlpb
  float*  partA  = (float*) (p + 89 * MB);    // 64 MB (z-stride 32 MB)
  ushort* mlpb   = (ushort*)(p + 89 * MB);    // 64 MB
  ushort* vT     = (ushort*)(p + 137 * MB);   // 16 MB  [dead after PV]
  ushort* wqkvb  = (ushort*)(p + 153 * MB);   // 24 MB  [dead after QKV]
  float*  scores = (float*) (p + 153 * MB);   // 32 MB  [dead after softmax]
  ushort* ctx    = (ushort*)(p + 153 * MB);   // 16 MB  [dead after attn-out]
  float*  partM0 = (float*) (p + 0 * MB);     // 32 MB  (wdb/w1b dead by mlp2)
  float*  partM1 = (float*) (p + 153 * MB);   // 32 MB
  float*  h      = (float*) (p + 185 * MB);   // 32 MB  [live till end]
  ushort* hb     = (ushort*)(p + 217 * MB);   // 16 MB  [dead after mlp1]

  const dim3 blk(256), blk512(512);
  const long SQ = (long)SEQ * SEQ;

  // ---- bf16 conversions ----
  cvt8<<<4096, blk, 0, stream>>>(x, xb);
  cvt8<<<2048, blk, 0, stream>>>(wq, wqkvb);
  cvt8<<<2048, blk, 0, stream>>>(wk, wqkvb + 4194304);
  cvt8<<<2048, blk, 0, stream>>>(wv, wqkvb + 8388608);
  cvt8<<<2048, blk, 0, stream>>>(wd, wdb);
  cvt8<<<8192, blk, 0, stream>>>(w1, w1b);
  cvt8<<<8192, blk, 0, stream>>>(w2, w2b);
  concat3<<<24, blk, 0, stream>>>(bq, bk, bv, bqkv);

  // fused QKV: [4096,2048] x [6144,2048]^T -> qkv bf16 [4096][6144]
  gemm256<EPI_QKV><<<dim3(24, 16, 1), blk512, 131072, stream>>>(
      xb, wqkvb, bqkv, qkv, 6144, 2048, 2048, 2048, 6144, 0, 0, 0, 1.f);

  transpose_v<<<dim3(64, 64, 2), blk, 0, stream>>>(qkv, vT);

  // scores = q k^T / sqrt(E), per batch
  gemm_bt<EPI_SCORES><<<dim3(16, 16, 2), blk, 0, stream>>>(
      qkv, qkv + 2048, nullptr, nullptr, scores, 2048, 2048, 6144, 6144, 2048,
      2048L * 6144, 2048L * 6144, SQ, 0.022097086912079608f);

  softmax_rows<<<dim3(4096), blk, 0, stream>>>(scores, probs);

  // ctx = probs @ v
  gemm_bt<EPI_PV><<<dim3(16, 16, 2), blk, 0, stream>>>(
      probs, vT, nullptr, nullptr, ctx, 2048, 2048, 2048, 2048, 2048,
      SQ, SQ, SQ, 1.f);

  // attn-out, split-K=2: partA[z] = ctx[:, z*1024:+1024] @ wd^T-slice
  gemm256<EPI_SCORES><<<dim3(8, 16, 2), blk512, 131072, stream>>>(
      ctx, wdb, nullptr, partA, 2048, 1024, 2048, 2048, 2048,
      1024, 1024, 8388608, 1.f);

  // h = LN(partA0 + partA1 + bd + x); hb = bf16(h)
  layernorm_fused<<<4096, blk, 0, stream>>>(
      partA, partA + 8388608, bd, x, ln_g, ln_b, h, hb);

  // mlpb = gelu(h @ w1^T + b1)
  gemm256<EPI_GELU><<<dim3(32, 16, 1), blk512, 131072, stream>>>(
      hb, w1b, b1, mlpb, 8192, 2048, 2048, 2048, 8192, 0, 0, 0, 1.f);

  // mlp2, split-K=2: partM[z] = mlpb[:, z*4096:+4096] @ w2^T-slice
  gemm256<EPI_SCORES><<<dim3(8, 16, 2), blk512, 131072, stream>>>(
      mlpb, w2b, nullptr, partM0, 2048, 4096, 8192, 8192, 2048,
      4096, 4096, (long)(153 * MB / 4), 1.f);
  // out = partM0 + partM1 + b2 + h
  reduce2<<<4096, blk, 0, stream>>>(partM0, partM1, b2, h, out);
}